// Round 21
// baseline (37.342 us; speedup 1.0000x reference)
//
#include <hip/hip_runtime.h>
#include <stdint.h>

// MetricLoss: B=1024, M=32, F=256, K_GRP=4
// out[0] = (1/1536) * sum_{same-group pairs i<j, m} ||x_i,m - x_j,m||^2
// out[1] = (1/522240) * sum_{g_i<g_j, m} relu(1 - ||x_i,m - x_j,m||^2)
//
// R21 = R18 + NONTEMPORAL producer stores. Cross-round algebra (R18+R19):
// heter_cold ~28-30us vs heter_warm ~10us -- the cold pass reads xq/sq that
// sit DIRTY in producer XCDs' L2s -> cross-XCD coherence probes. nt stores
// (evict-first) keep the lines out of the producer L2 so consumer reads are
// clean L3/HBM hits. Single variable vs R18 (35.2us best).
//
// ws layout:
//   [0,        8 MiB)    : xq  fp8 e4m3 [32][1024][256]
//   [8 MiB,  +128 KiB)   : sq  f32 [32][1024]
//   [+32 KiB]            : homo_part  f32 [8192]
//   [+4.5 KiB]           : heter_part f32 [1152]

typedef __attribute__((ext_vector_type(4))) float f32x4;

#define XQ_OFF    0u
#define SQ_OFF    8388608u
#define HOMO_OFF  8519680u    // 8192 floats
#define HETER_OFF 8552448u    // 1152 floats

#define AS1 __attribute__((address_space(1)))
#define AS3 __attribute__((address_space(3)))

__device__ __forceinline__ void async16(const void* g, void* l) {
  __builtin_amdgcn_global_load_lds((const AS1 unsigned int*)(uintptr_t)g,
                                   (AS3 unsigned int*)(uintptr_t)l, 16, 0, 0);
}

// ---- Kernel 1 (fused convert-to-fp8 + homo + sq), nt stores for xq/sq
__global__ __launch_bounds__(256) void k_fused(const float* __restrict__ x,
                                               unsigned char* __restrict__ xq,
                                               float* __restrict__ sq,
                                               float* __restrict__ homo_part) {
  const int task = blockIdx.x * 4 + (threadIdx.x >> 6);  // task = g*32 + m
  const int lane = threadIdx.x & 63;
  const int g = task >> 5;
  const int m = task & 31;

  const float* base = x + ((size_t)(g * 4) * 32 + m) * 256 + lane * 4;
  float4 v[4];
  float sqv[4];
  #pragma unroll
  for (int a = 0; a < 4; ++a) {
    v[a] = *(const float4*)(base + a * 8192);
    float s = v[a].x * v[a].x + v[a].y * v[a].y + v[a].z * v[a].z + v[a].w * v[a].w;
    #pragma unroll
    for (int off = 32; off; off >>= 1) s += __shfl_xor(s, off, 64);
    sqv[a] = s;
    const int i = g * 4 + a;
    if (lane == 0)
      __builtin_nontemporal_store(s, sq + m * 1024 + i);
    int dw = __builtin_amdgcn_cvt_pk_fp8_f32(v[a].x, v[a].y, 0, false);
    dw = __builtin_amdgcn_cvt_pk_fp8_f32(v[a].z, v[a].w, dw, true);
    __builtin_nontemporal_store((unsigned)dw,
        (unsigned*)(xq + ((size_t)(m * 1024 + i)) * 256 + lane * 4));
  }
  const float sx = v[0].x + v[1].x + v[2].x + v[3].x;
  const float sy = v[0].y + v[1].y + v[2].y + v[3].y;
  const float sz = v[0].z + v[1].z + v[2].z + v[3].z;
  const float sw = v[0].w + v[1].w + v[2].w + v[3].w;
  float s = sx * sx + sy * sy + sz * sz + sw * sw;
  #pragma unroll
  for (int off = 32; off; off >>= 1) s += __shfl_xor(s, off, 64);
  if (lane == 0)
    homo_part[task] = 4.f * (sqv[0] + sqv[1] + sqv[2] + sqv[3]) - s;
}

// Stage one 8 KB fp8 panel-step (128 rows x 64 k) into an LDS buffer.
__device__ __forceinline__ void stage_panel(const unsigned char* __restrict__ X,
                                            int k0, unsigned char* buf, int tid) {
  #pragma unroll
  for (int i = 0; i < 2; ++i) {
    const int ch = i * 256 + tid;            // 512 chunks of 16B
    const int row = ch >> 2;
    const int gc = (ch & 3) ^ ((row >> 1) & 3);
    async16(X + (size_t)row * 256 + k0 + gc * 16, buf + ch * 16);
  }
}

// ---- Kernel 2: heter loss, fp8, BK=64, 2-deep counted-vmcnt pipeline.
__global__ __launch_bounds__(256) void k_heter(const unsigned char* __restrict__ xq,
                                               const float* __restrict__ sq,
                                               float* __restrict__ heter_part) {
  const int d = blockIdx.x;                  // 1152 = 8 * 144
  const int w = (d & 7) * 144 + (d >> 3);    // XCD chunk map (bijective)
  const int m = w / 36;
  int t0 = w - m * 36, r = 0;                // triangle decode: (r,c), c>=r
  while (t0 >= 8 - r) { t0 -= 8 - r; ++r; }
  const int cb = r + t0;
  const bool diag = (cb == r);

  __shared__ __align__(16) unsigned char A0[8192], A1[8192];  // 8 KB each
  __shared__ __align__(16) unsigned char B0[8192], B1[8192];
  __shared__ __align__(16) float sql[1024];                   // 4 KB sq row
  __shared__ float part[4];

  const int tid = threadIdx.x;
  const int lane = tid & 63;
  const int wid = tid >> 6;
  const int wr = wid >> 1, wc = wid & 1;     // 2x2 waves, each 64x64 output
  const int fr = lane & 15;
  const int kg = lane >> 4;

  const unsigned char* Xa = xq + ((size_t)m * 1024 + r  * 128) * 256;
  const unsigned char* Xb = xq + ((size_t)m * 1024 + cb * 128) * 256;

  // prologue: sq row + steps 0,1 of both panels
  async16(sq + m * 1024 + tid * 4, (char*)sql + tid * 16);
  stage_panel(Xa, 0, A0, tid);
  if (!diag) stage_panel(Xb, 0, B0, tid);
  stage_panel(Xa, 64, A1, tid);
  if (!diag) stage_panel(Xb, 64, B1, tid);

  f32x4 acc[4][4] = {};
  const int khalf = kg & 1;                  // low/high 8B within a 16B chunk

  #pragma unroll
  for (int s = 0; s < 4; ++s) {
    if (s < 3) {
      if (diag) asm volatile("s_waitcnt vmcnt(2)" ::: "memory");
      else      asm volatile("s_waitcnt vmcnt(4)" ::: "memory");
    } else {
      asm volatile("s_waitcnt vmcnt(0)" ::: "memory");
    }
    __builtin_amdgcn_s_barrier();
    asm volatile("" ::: "memory");

    const unsigned char* lA = (s & 1) ? A1 : A0;
    const unsigned char* lB = diag ? lA : ((s & 1) ? B1 : B0);
    #pragma unroll
    for (int ks = 0; ks < 2; ++ks) {
      long af[4], bv[4];
      #pragma unroll
      for (int q = 0; q < 4; ++q) {
        const int ra = wr * 64 + q * 16 + fr;
        const int ca = (2 * ks + (kg >> 1)) ^ ((ra >> 1) & 3);
        af[q] = *(const long*)(lA + ra * 64 + ca * 16 + khalf * 8);
        const int rb = wc * 64 + q * 16 + fr;
        const int cbx = (2 * ks + (kg >> 1)) ^ ((rb >> 1) & 3);
        bv[q] = *(const long*)(lB + rb * 64 + cbx * 16 + khalf * 8);
      }
      #pragma unroll
      for (int ai = 0; ai < 4; ++ai)
        #pragma unroll
        for (int bj = 0; bj < 4; ++bj)
          acc[ai][bj] = __builtin_amdgcn_mfma_f32_16x16x32_fp8_fp8(af[ai], bv[bj],
                                                                   acc[ai][bj], 0, 0, 0);
    }

    asm volatile("" ::: "memory");
    __builtin_amdgcn_s_barrier();            // all waves done reading step-s bufs
    asm volatile("" ::: "memory");
    if (s + 2 < 4) {                         // refill freed buffers with step s+2
      stage_panel(Xa, (s + 2) * 64, (s & 1) ? A1 : A0, tid);
      if (!diag) stage_panel(Xb, (s + 2) * 64, (s & 1) ? B1 : B0, tid);
    }
  }

  // epilogue: relu(1 - (sq_i + sq_j - 2*dot)), group mask, reduce
  const int ibase = r  * 128 + wr * 64;
  const int jbase = cb * 128 + wc * 64;
  float sqi[4][4];
  #pragma unroll
  for (int ai = 0; ai < 4; ++ai)
    #pragma unroll
    for (int rg = 0; rg < 4; ++rg)
      sqi[ai][rg] = sql[ibase + ai * 16 + kg * 4 + rg];

  float local = 0.f;
  if (!diag) {
    // c > r  =>  gj > gi for every (i,j) in this tile: branchless hinge.
    #pragma unroll
    for (int bj = 0; bj < 4; ++bj) {
      const float omsqj = 1.f - sql[jbase + bj * 16 + fr];
      #pragma unroll
      for (int ai = 0; ai < 4; ++ai)
        #pragma unroll
        for (int rg = 0; rg < 4; ++rg)
          local += fmaxf(fmaf(2.f, acc[ai][bj][rg], omsqj - sqi[ai][rg]), 0.f);
    }
  } else {
    #pragma unroll
    for (int bj = 0; bj < 4; ++bj) {
      const int j = jbase + bj * 16 + fr;    // C/D: col = lane&15
      const float sqj = sql[j];
      const int gj = j >> 2;
      #pragma unroll
      for (int ai = 0; ai < 4; ++ai)
        #pragma unroll
        for (int rg = 0; rg < 4; ++rg) {
          const int i = ibase + ai * 16 + kg * 4 + rg;  // row=(lane>>4)*4+reg
          const float dd = sqi[ai][rg] + sqj - 2.f * acc[ai][bj][rg];
          const float v = 1.f - dd;
          if (v > 0.f && gj > (i >> 2)) local += v;
        }
    }
  }
  #pragma unroll
  for (int off = 32; off; off >>= 1) local += __shfl_xor(local, off, 64);
  if (lane == 0) part[wid] = local;
  __syncthreads();
  if (tid == 0) heter_part[w] = part[0] + part[1] + part[2] + part[3];
}

// ---- Kernel 3: final reduction of partials + scaling (single block)
__global__ __launch_bounds__(256) void k_final(const float* __restrict__ homo_part,
                                               const float* __restrict__ heter_part,
                                               float* __restrict__ out) {
  __shared__ float red[8];
  const int tid = threadIdx.x;
  const int lane = tid & 63;
  const int wid = tid >> 6;

  float h = 0.f;
  for (int i = tid; i < 8192; i += 256) h += homo_part[i];
  #pragma unroll
  for (int off = 32; off; off >>= 1) h += __shfl_xor(h, off, 64);
  if (lane == 0) red[wid] = h;

  float e = 0.f;
  for (int i = tid; i < 1152; i += 256) e += heter_part[i];
  #pragma unroll
  for (int off = 32; off; off >>= 1) e += __shfl_xor(e, off, 64);
  if (lane == 0) red[4 + wid] = e;

  __syncthreads();
  if (tid == 0) out[0] = (red[0] + red[1] + red[2] + red[3]) * (1.0f / 1536.0f);
  if (tid == 1) out[1] = (red[4] + red[5] + red[6] + red[7]) * (1.0f / 522240.0f);
}

extern "C" void kernel_launch(void* const* d_in, const int* in_sizes, int n_in,
                              void* d_out, int out_size, void* d_ws, size_t ws_size,
                              hipStream_t stream) {
  const float* x = (const float*)d_in[0];
  float* out = (float*)d_out;
  char* ws = (char*)d_ws;
  unsigned char* xq = (unsigned char*)(ws + XQ_OFF);
  float* sq         = (float*)(ws + SQ_OFF);
  float* homo_part  = (float*)(ws + HOMO_OFF);
  float* heter_part = (float*)(ws + HETER_OFF);

  k_fused<<<2048, 256, 0, stream>>>(x, xq, sq, homo_part);
  k_heter<<<1152, 256, 0, stream>>>(xq, sq, heter_part);
  k_final<<<1, 256, 0, stream>>>(homo_part, heter_part, out);
}

// Round 22
// 34.592 us; speedup vs baseline: 1.0795x; 1.0795x over previous
//
#include <hip/hip_runtime.h>
#include <stdint.h>

// MetricLoss: B=1024, M=32, F=256, K_GRP=4
// out[0] = (1/1536) * sum_{same-group pairs i<j, m} ||x_i,m - x_j,m||^2
// out[1] = (1/522240) * sum_{g_i<g_j, m} relu(1 - ||x_i,m - x_j,m||^2)
//
// R22 = exact revert to R18 (best clean measured config, 35.2us):
// fp8 e4m3 Gram (hinge margin ~11 sigma -> numerically free; homo exact f32),
// k_heter: BK=64 2-deep counted-vmcnt pipeline, 37 KB LDS, no spills.
// R19's direct measurement of this structure: heter 14us/rep warm, Mfma 26%,
// VALU 28%, Occ 15%, FETCH 4.2MB -> no saturated pipe; residual vs ~20us
// bottom-up floor is inter-node gaps + per-replay cold-cache tax from the
// harness ws-poison fills (40us fillBufferAligned walls in every profile).
// Probed null levers: XCD remap, nt stores, branchless epilogue, barrier-free,
// byte halving, 4 blk/CU. Shipping the best-known config.
//
// ws layout:
//   [0,        8 MiB)    : xq  fp8 e4m3 [32][1024][256]
//   [8 MiB,  +128 KiB)   : sq  f32 [32][1024]
//   [+32 KiB]            : homo_part  f32 [8192]
//   [+4.5 KiB]           : heter_part f32 [1152]

typedef __attribute__((ext_vector_type(4))) float f32x4;

#define XQ_OFF    0u
#define SQ_OFF    8388608u
#define HOMO_OFF  8519680u    // 8192 floats
#define HETER_OFF 8552448u    // 1152 floats

#define AS1 __attribute__((address_space(1)))
#define AS3 __attribute__((address_space(3)))

__device__ __forceinline__ void async16(const void* g, void* l) {
  __builtin_amdgcn_global_load_lds((const AS1 unsigned int*)(uintptr_t)g,
                                   (AS3 unsigned int*)(uintptr_t)l, 16, 0, 0);
}

// ---- Kernel 1 (fused convert-to-fp8 + homo + sq)
__global__ __launch_bounds__(256) void k_fused(const float* __restrict__ x,
                                               unsigned char* __restrict__ xq,
                                               float* __restrict__ sq,
                                               float* __restrict__ homo_part) {
  const int task = blockIdx.x * 4 + (threadIdx.x >> 6);  // task = g*32 + m
  const int lane = threadIdx.x & 63;
  const int g = task >> 5;
  const int m = task & 31;

  const float* base = x + ((size_t)(g * 4) * 32 + m) * 256 + lane * 4;
  float4 v[4];
  float sqv[4];
  #pragma unroll
  for (int a = 0; a < 4; ++a) {
    v[a] = *(const float4*)(base + a * 8192);
    float s = v[a].x * v[a].x + v[a].y * v[a].y + v[a].z * v[a].z + v[a].w * v[a].w;
    #pragma unroll
    for (int off = 32; off; off >>= 1) s += __shfl_xor(s, off, 64);
    sqv[a] = s;
    const int i = g * 4 + a;
    if (lane == 0) sq[m * 1024 + i] = s;
    int dw = __builtin_amdgcn_cvt_pk_fp8_f32(v[a].x, v[a].y, 0, false);
    dw = __builtin_amdgcn_cvt_pk_fp8_f32(v[a].z, v[a].w, dw, true);
    *(unsigned*)(xq + ((size_t)(m * 1024 + i)) * 256 + lane * 4) = (unsigned)dw;
  }
  const float sx = v[0].x + v[1].x + v[2].x + v[3].x;
  const float sy = v[0].y + v[1].y + v[2].y + v[3].y;
  const float sz = v[0].z + v[1].z + v[2].z + v[3].z;
  const float sw = v[0].w + v[1].w + v[2].w + v[3].w;
  float s = sx * sx + sy * sy + sz * sz + sw * sw;
  #pragma unroll
  for (int off = 32; off; off >>= 1) s += __shfl_xor(s, off, 64);
  if (lane == 0)
    homo_part[task] = 4.f * (sqv[0] + sqv[1] + sqv[2] + sqv[3]) - s;
}

// Stage one 8 KB fp8 panel-step (128 rows x 64 k) into an LDS buffer.
// Rows are 64 B = 4 chunks of 16B; chunk swizzle key (row>>1)&3 makes the
// b64 fragment reads 2-way (free). 2 async16 per thread.
__device__ __forceinline__ void stage_panel(const unsigned char* __restrict__ X,
                                            int k0, unsigned char* buf, int tid) {
  #pragma unroll
  for (int i = 0; i < 2; ++i) {
    const int ch = i * 256 + tid;            // 512 chunks of 16B
    const int row = ch >> 2;
    const int gc = (ch & 3) ^ ((row >> 1) & 3);
    async16(X + (size_t)row * 256 + k0 + gc * 16, buf + ch * 16);
  }
}

// ---- Kernel 2: heter loss, fp8, BK=64, 2-deep counted-vmcnt pipeline.
__global__ __launch_bounds__(256) void k_heter(const unsigned char* __restrict__ xq,
                                               const float* __restrict__ sq,
                                               float* __restrict__ heter_part) {
  const int d = blockIdx.x;                  // 1152 = 8 * 144
  const int w = (d & 7) * 144 + (d >> 3);    // XCD chunk map (bijective)
  const int m = w / 36;
  int t0 = w - m * 36, r = 0;                // triangle decode: (r,c), c>=r
  while (t0 >= 8 - r) { t0 -= 8 - r; ++r; }
  const int cb = r + t0;
  const bool diag = (cb == r);

  __shared__ __align__(16) unsigned char A0[8192], A1[8192];  // 8 KB each
  __shared__ __align__(16) unsigned char B0[8192], B1[8192];
  __shared__ __align__(16) float sql[1024];                   // 4 KB sq row
  __shared__ float part[4];

  const int tid = threadIdx.x;
  const int lane = tid & 63;
  const int wid = tid >> 6;
  const int wr = wid >> 1, wc = wid & 1;     // 2x2 waves, each 64x64 output
  const int fr = lane & 15;
  const int kg = lane >> 4;

  const unsigned char* Xa = xq + ((size_t)m * 1024 + r  * 128) * 256;
  const unsigned char* Xb = xq + ((size_t)m * 1024 + cb * 128) * 256;

  // prologue: sq row + steps 0,1 of both panels
  async16(sq + m * 1024 + tid * 4, (char*)sql + tid * 16);
  stage_panel(Xa, 0, A0, tid);
  if (!diag) stage_panel(Xb, 0, B0, tid);
  stage_panel(Xa, 64, A1, tid);
  if (!diag) stage_panel(Xb, 64, B1, tid);

  f32x4 acc[4][4] = {};
  const int khalf = kg & 1;                  // low/high 8B within a 16B chunk

  #pragma unroll
  for (int s = 0; s < 4; ++s) {
    if (s < 3) {
      if (diag) asm volatile("s_waitcnt vmcnt(2)" ::: "memory");
      else      asm volatile("s_waitcnt vmcnt(4)" ::: "memory");
    } else {
      asm volatile("s_waitcnt vmcnt(0)" ::: "memory");
    }
    __builtin_amdgcn_s_barrier();
    asm volatile("" ::: "memory");

    const unsigned char* lA = (s & 1) ? A1 : A0;
    const unsigned char* lB = diag ? lA : ((s & 1) ? B1 : B0);
    #pragma unroll
    for (int ks = 0; ks < 2; ++ks) {
      long af[4], bv[4];
      #pragma unroll
      for (int q = 0; q < 4; ++q) {
        const int ra = wr * 64 + q * 16 + fr;
        const int ca = (2 * ks + (kg >> 1)) ^ ((ra >> 1) & 3);
        af[q] = *(const long*)(lA + ra * 64 + ca * 16 + khalf * 8);
        const int rb = wc * 64 + q * 16 + fr;
        const int cbx = (2 * ks + (kg >> 1)) ^ ((rb >> 1) & 3);
        bv[q] = *(const long*)(lB + rb * 64 + cbx * 16 + khalf * 8);
      }
      #pragma unroll
      for (int ai = 0; ai < 4; ++ai)
        #pragma unroll
        for (int bj = 0; bj < 4; ++bj)
          acc[ai][bj] = __builtin_amdgcn_mfma_f32_16x16x32_fp8_fp8(af[ai], bv[bj],
                                                                   acc[ai][bj], 0, 0, 0);
    }

    asm volatile("" ::: "memory");
    __builtin_amdgcn_s_barrier();            // all waves done reading step-s bufs
    asm volatile("" ::: "memory");
    if (s + 2 < 4) {                         // refill freed buffers with step s+2
      stage_panel(Xa, (s + 2) * 64, (s & 1) ? A1 : A0, tid);
      if (!diag) stage_panel(Xb, (s + 2) * 64, (s & 1) ? B1 : B0, tid);
    }
  }

  // epilogue: relu(1 - (sq_i + sq_j - 2*dot)), strict group mask, reduce
  const int ibase = r  * 128 + wr * 64;
  const int jbase = cb * 128 + wc * 64;
  float sqi[4][4];
  #pragma unroll
  for (int ai = 0; ai < 4; ++ai)
    #pragma unroll
    for (int rg = 0; rg < 4; ++rg)
      sqi[ai][rg] = sql[ibase + ai * 16 + kg * 4 + rg];

  float local = 0.f;
  #pragma unroll
  for (int bj = 0; bj < 4; ++bj) {
    const int j = jbase + bj * 16 + fr;      // C/D: col = lane&15
    const float sqj = sql[j];
    const int gj = j >> 2;
    #pragma unroll
    for (int ai = 0; ai < 4; ++ai)
      #pragma unroll
      for (int rg = 0; rg < 4; ++rg) {
        const int i = ibase + ai * 16 + kg * 4 + rg;  // row = (lane>>4)*4 + reg
        const float dd = sqi[ai][rg] + sqj - 2.f * acc[ai][bj][rg];
        const float v = 1.f - dd;
        if (v > 0.f && gj > (i >> 2)) local += v;
      }
  }
  #pragma unroll
  for (int off = 32; off; off >>= 1) local += __shfl_xor(local, off, 64);
  if (lane == 0) part[wid] = local;
  __syncthreads();
  if (tid == 0) heter_part[w] = part[0] + part[1] + part[2] + part[3];
}

// ---- Kernel 3: final reduction of partials + scaling (single block)
__global__ __launch_bounds__(256) void k_final(const float* __restrict__ homo_part,
                                               const float* __restrict__ heter_part,
                                               float* __restrict__ out) {
  __shared__ float red[8];
  const int tid = threadIdx.x;
  const int lane = tid & 63;
  const int wid = tid >> 6;

  float h = 0.f;
  for (int i = tid; i < 8192; i += 256) h += homo_part[i];
  #pragma unroll
  for (int off = 32; off; off >>= 1) h += __shfl_xor(h, off, 64);
  if (lane == 0) red[wid] = h;

  float e = 0.f;
  for (int i = tid; i < 1152; i += 256) e += heter_part[i];
  #pragma unroll
  for (int off = 32; off; off >>= 1) e += __shfl_xor(e, off, 64);
  if (lane == 0) red[4 + wid] = e;

  __syncthreads();
  if (tid == 0) out[0] = (red[0] + red[1] + red[2] + red[3]) * (1.0f / 1536.0f);
  if (tid == 1) out[1] = (red[4] + red[5] + red[6] + red[7]) * (1.0f / 522240.0f);
}

extern "C" void kernel_launch(void* const* d_in, const int* in_sizes, int n_in,
                              void* d_out, int out_size, void* d_ws, size_t ws_size,
                              hipStream_t stream) {
  const float* x = (const float*)d_in[0];
  float* out = (float*)d_out;
  char* ws = (char*)d_ws;
  unsigned char* xq = (unsigned char*)(ws + XQ_OFF);
  float* sq         = (float*)(ws + SQ_OFF);
  float* homo_part  = (float*)(ws + HOMO_OFF);
  float* heter_part = (float*)(ws + HETER_OFF);

  k_fused<<<2048, 256, 0, stream>>>(x, xq, sq, homo_part);
  k_heter<<<1152, 256, 0, stream>>>(xq, sq, heter_part);
  k_final<<<1, 256, 0, stream>>>(homo_part, heter_part, out);
}